// Round 9
// baseline (645.484 us; speedup 1.0000x reference)
//
#include <hip/hip_runtime.h>
#include <hip/hip_fp16.h>

#define CAP 128   // max in-degree handled by the fast LDS path

// ---------------- tiled GEMM + attention logits ----------------
// hp written as TWO fp16 half-tables hpA (ch 0-31), hpB (ch 32-63), 3.2 MB each
// so the node_agg gather table fits a 4 MB per-XCD L2.
template<int K, bool APPLY_BN>
__global__ void __launch_bounds__(256, 4)
gemm_tiled(const float* __restrict__ X, const float* __restrict__ W,
           const float* __restrict__ a_s, const float* __restrict__ a_d,
           const float* __restrict__ bnsum, const float* __restrict__ bnsq,
           const float* __restrict__ g, const float* __restrict__ be,
           __half* __restrict__ hpA, __half* __restrict__ hpB,
           float* __restrict__ al_s, float* __restrict__ al_d, int n)
{
  __shared__ float Wl[(K / 4) * 64 * 4];  // [(k4*64+lane)*4+c] = W[(k4*4+c)*64+lane]
  __shared__ float Xt[64 * K];            // row-major [64][K]

  for (int gi = threadIdx.x; gi < (K / 4) * 64; gi += 256) {
    int k4 = gi >> 6, ln = gi & 63;
    float4 w;
    w.x = W[(k4 * 4 + 0) * 64 + ln];
    w.y = W[(k4 * 4 + 1) * 64 + ln];
    w.z = W[(k4 * 4 + 2) * 64 + ln];
    w.w = W[(k4 * 4 + 3) * 64 + ln];
    *(float4*)&Wl[gi * 4] = w;
  }

  int row0 = blockIdx.x * 64;
  int nrows = min(64, n - row0);
  float4 sc, sh;
  if (APPLY_BN) {   // K==64 path: float4 col group fixed per thread
    int cg = (threadIdx.x & 15) * 4;
    float inv_n = 1.f / (float)n;
#pragma unroll
    for (int q = 0; q < 4; ++q) {
      float mu  = bnsum[cg + q] * inv_n;
      float var = bnsq[cg + q] * inv_n - mu * mu;
      float s   = g[cg + q] * rsqrtf(var + 1e-5f);
      ((float*)&sc)[q] = s;
      ((float*)&sh)[q] = be[cg + q] - mu * s;
    }
  }
  const float4* src = (const float4*)(X + (size_t)row0 * K);
  int nf4 = nrows * (K / 4);
  for (int i = threadIdx.x; i < nf4; i += 256) {
    float4 v = src[i];
    if (APPLY_BN) {
      v.x = fmaxf(v.x * sc.x + sh.x, 0.f);
      v.y = fmaxf(v.y * sc.y + sh.y, 0.f);
      v.z = fmaxf(v.z * sc.z + sh.z, 0.f);
      v.w = fmaxf(v.w * sc.w + sh.w, 0.f);
    }
    *(float4*)&Xt[i * 4] = v;
  }
  __syncthreads();

  int lane = threadIdx.x & 63;
  int wid  = threadIdx.x >> 6;
  int rbase = wid * 16;
  float acc[16];
#pragma unroll
  for (int r = 0; r < 16; ++r) acc[r] = 0.f;

  for (int k4 = 0; k4 < K / 4; ++k4) {
    float4 wv = *(const float4*)&Wl[(k4 * 64 + lane) * 4];
#pragma unroll
    for (int r = 0; r < 16; ++r) {
      float4 xv = *(const float4*)&Xt[(rbase + r) * K + k4 * 4];
      acc[r] += xv.x * wv.x + xv.y * wv.y + xv.z * wv.z + xv.w * wv.w;
    }
  }

  float as_l = a_s[lane], ad_l = a_d[lane];
  int h = lane >> 4, c = lane & 15;
#pragma unroll
  for (int r = 0; r < 16; ++r) {
    int lr = rbase + r;
    if (lr >= nrows) break;
    int row = row0 + lr;
    float a = acc[r];
    if (lane < 32) hpA[(size_t)row * 32 + lane] = __float2half(a);
    else           hpB[(size_t)row * 32 + (lane - 32)] = __float2half(a);
    float vs = a * as_l;
    float vd = a * ad_l;
#pragma unroll
    for (int off = 8; off >= 1; off >>= 1) {
      vs += __shfl_xor(vs, off, 64);
      vd += __shfl_xor(vd, off, 64);
    }
    if (c == 0) { al_s[row * 4 + h] = vs; al_d[row * 4 + h] = vd; }
  }
}

// ---------------- CSR build (once per call; reused by both layers) ----------------
__global__ void hist_k(const int* __restrict__ ei, int E, int N, int* __restrict__ count)
{
  int e = blockIdx.x * 256 + threadIdx.x;
  int Et = E + N;
  if (e >= Et) return;
  int d = (e < E) ? ei[E + e] : (e - E);
  atomicAdd(&count[d], 1);
}

__global__ void scan_block_k(const int* __restrict__ count, int* __restrict__ row_ptr,
                             int* __restrict__ partial, int n)
{
  __shared__ int woff[16];
  int tid = threadIdx.x;
  int i = blockIdx.x * 1024 + tid;
  int v = (i < n) ? count[i] : 0;
  int lane = tid & 63, wid = tid >> 6;
  int incl = v;
#pragma unroll
  for (int off = 1; off < 64; off <<= 1) {
    int t = __shfl_up(incl, off, 64);
    if (lane >= off) incl += t;
  }
  if (lane == 63) woff[wid] = incl;
  __syncthreads();
  if (tid < 16) {
    int wv = woff[tid];
    int winc = wv;
#pragma unroll
    for (int off = 1; off < 16; off <<= 1) {
      int t = __shfl_up(winc, off, 64);
      if (tid >= off) winc += t;
    }
    woff[tid] = winc - wv;
    if (tid == 15) partial[blockIdx.x] = winc;
  }
  __syncthreads();
  if (i < n) row_ptr[i] = woff[wid] + incl - v;
}

__global__ void scan_partial_k(int* __restrict__ partial, int* __restrict__ row_ptr,
                               int nb, int n)
{
  int tid = threadIdx.x;  // 64 threads
  int v = (tid < nb) ? partial[tid] : 0;
  int incl = v;
#pragma unroll
  for (int off = 1; off < 64; off <<= 1) {
    int t = __shfl_up(incl, off, 64);
    if (tid >= off) incl += t;
  }
  if (tid < nb) partial[tid] = incl - v;
  if (tid == 63) row_ptr[n] = incl;
}

__global__ void scan_add_k(int* __restrict__ row_ptr, int* __restrict__ cursor,
                           const int* __restrict__ partial, int n)
{
  int i = blockIdx.x * 1024 + threadIdx.x;
  if (i < n) {
    int r = row_ptr[i] + partial[blockIdx.x];
    row_ptr[i] = r;
    cursor[i] = r;
  }
}

__global__ void scatter_k(const int* __restrict__ ei, int E, int N,
                          int* __restrict__ cursor, int* __restrict__ col_src)
{
  int e = blockIdx.x * 256 + threadIdx.x;
  int Et = E + N;
  if (e >= Et) return;
  int s, d;
  if (e < E) { s = ei[e]; d = ei[E + e]; } else { s = d = e - E; }
  int pos = atomicAdd(&cursor[d], 1);
  col_src[pos] = s;
}

// ---------------- per-node softmax weights + denominators ----------------
// Node-parallel (one wave per node): lanes gather al_s[src] (L2-resident),
// compute exp(leaky(.)), write CSR-ordered float2 weight halves (heads 0/1 ->
// ewA, heads 2/3 -> ewB, both coalesced), wave-reduce the per-head sums and
// write den[d] directly — no atomics, and node_agg loses its whole
// stage-reduce serial chain.
__global__ void __launch_bounds__(256)
ew_den_k(const int* __restrict__ row_ptr, const int* __restrict__ col_src,
         const float* __restrict__ al_s, const float* __restrict__ al_d,
         float2* __restrict__ ewA, float2* __restrict__ ewB,
         float2* __restrict__ denA, float2* __restrict__ denB, int n)
{
  int lane = threadIdx.x & 63;
  int wid  = threadIdx.x >> 6;
  int nwaves = gridDim.x * 4;
  for (int d = blockIdx.x * 4 + wid; d < n; d += nwaves) {
    int beg = row_ptr[d], end = row_ptr[d + 1];
    int deg = end - beg;
    float4 ald4 = *(const float4*)(al_d + (size_t)d * 4);
    float s0 = 0.f, s1 = 0.f, s2 = 0.f, s3 = 0.f;
    for (int jb = 0; jb < deg; jb += 64) {
      int jj = jb + lane;
      if (jj < deg) {
        int s = col_src[beg + jj];
        float4 a = *(const float4*)(al_s + (size_t)s * 4);
        float ex = a.x + ald4.x; ex = ex >= 0.f ? ex : 0.2f * ex;
        float ey = a.y + ald4.y; ey = ey >= 0.f ? ey : 0.2f * ey;
        float ez = a.z + ald4.z; ez = ez >= 0.f ? ez : 0.2f * ez;
        float ew = a.w + ald4.w; ew = ew >= 0.f ? ew : 0.2f * ew;
        ex = __expf(ex); ey = __expf(ey); ez = __expf(ez); ew = __expf(ew);
        ewA[beg + jj] = make_float2(ex, ey);
        ewB[beg + jj] = make_float2(ez, ew);
        s0 += ex; s1 += ey; s2 += ez; s3 += ew;
      }
    }
#pragma unroll
    for (int off = 32; off >= 1; off >>= 1) {
      s0 += __shfl_xor(s0, off, 64);
      s1 += __shfl_xor(s1, off, 64);
      s2 += __shfl_xor(s2, off, 64);
      s3 += __shfl_xor(s3, off, 64);
    }
    if (lane == 0) {
      denA[d] = make_float2(s0, s1);
      denB[d] = make_float2(s2, s3);
    }
  }
}

// ---------------- per-node aggregation (split channels, pure gather) ----------
// PASS 0: channels 0-31 from hpA (heads 0/1); PASS 1: channels 32-63 from hpB.
// Each 3.2 MB half-table fits per-XCD L2 -> gathers are L2-hits.
// lane = (edge-parity)*32 + channel: one 2B/lane load instruction covers TWO
// 64B rows. Stage col_src+float2 weights into LDS (zero-padded to x8);
// 4 independent gathers per unrolled step; one shfl_xor(32) folds parities.
template<int PASS>
__global__ void __launch_bounds__(256)
node_agg(const int* __restrict__ row_ptr, const int* __restrict__ col_src,
         const float2* __restrict__ ew2, const float2* __restrict__ den2,
         const __half* __restrict__ hph, const float* __restrict__ bias,
         float* __restrict__ hpre, float* __restrict__ bnsum, float* __restrict__ bnsq,
         int n)
{
  __shared__ int   sh_s[4][CAP];
  __shared__ float sh_w[4][CAP * 2];
  __shared__ float shs[64], shq[64];

  int lane = threadIdx.x & 63;
  int wid  = threadIdx.x >> 6;
  int c    = lane & 31;          // channel within half
  int e2   = lane >> 5;          // edge parity handled by this half-wave
  int h    = c >> 4;             // local head (0/1) within the pass
  float b  = bias[PASS * 32 + c];
  float lsum = 0.f, lsq = 0.f;
  int nwaves = gridDim.x * 4;

  for (int d = blockIdx.x * 4 + wid; d < n; d += nwaves) {
    int beg = row_ptr[d], end = row_ptr[d + 1];
    int deg = end - beg;
    float outv;
    float2 dn = den2[d];
    float den = h ? dn.y : dn.x;

    if (deg <= CAP) {
      int degR = (deg + 7) & ~7;
      for (int jb = 0; jb < degR; jb += 64) {
        int jj = jb + lane;
        if (jj < deg) {
          sh_s[wid][jj] = col_src[beg + jj];
          *(float2*)&sh_w[wid][jj * 2] = ew2[beg + jj];
        } else if (jj < degR) {
          sh_s[wid][jj] = 0;
          *(float2*)&sh_w[wid][jj * 2] = make_float2(0.f, 0.f);
        }
      }
      float acc = 0.f;
      for (int j = 0; j < degR; j += 8) {
#pragma unroll
        for (int k = 0; k < 4; ++k) {
          int e = j + k * 2 + e2;
          int s = sh_s[wid][e];
          float wh = sh_w[wid][e * 2 + h];
          acc += wh * __half2float(hph[(size_t)s * 32 + c]);
        }
      }
      acc += __shfl_xor(acc, 32, 64);
      outv = acc / (den + 1e-16f) + b;
    } else {
      // fallback: all lanes compute the full sum serially (no fold)
      float acc = 0.f;
      for (int j = beg; j < end; ++j) {
        float2 w2 = ew2[j];
        float wh = h ? w2.y : w2.x;
        acc += wh * __half2float(hph[(size_t)col_src[j] * 32 + c]);
      }
      outv = acc / (den + 1e-16f) + b;
    }

    if (lane < 32) {
      hpre[(size_t)d * 64 + PASS * 32 + c] = outv;
      lsum += outv; lsq += outv * outv;
    }
  }

  if (threadIdx.x < 64) { shs[threadIdx.x] = 0.f; shq[threadIdx.x] = 0.f; }
  __syncthreads();
  if (lane < 32) {
    atomicAdd(&shs[PASS * 32 + c], lsum);
    atomicAdd(&shq[PASS * 32 + c], lsq);
  }
  __syncthreads();
  if (threadIdx.x < 64) {
    atomicAdd(&bnsum[threadIdx.x], shs[threadIdx.x]);
    atomicAdd(&bnsq[threadIdx.x],  shq[threadIdx.x]);
  }
}

// ---------------- BatchNorm apply (final layer, in-place on out) ----------------
__global__ void bn_apply(float* __restrict__ buf, const float* __restrict__ bnsum,
                         const float* __restrict__ bnsq, const float* __restrict__ g,
                         const float* __restrict__ be, int n)
{
  size_t i = (size_t)blockIdx.x * 256 + threadIdx.x;
  size_t total = (size_t)n * 64;
  if (i >= total) return;
  int c = (int)(i & 63);
  float inv_n = 1.f / (float)n;
  float mu  = bnsum[c] * inv_n;
  float var = bnsq[c] * inv_n - mu * mu;    // biased var, matches jnp .var()
  buf[i] = (buf[i] - mu) * rsqrtf(var + 1e-5f) * g[c] + be[c];
}

extern "C" void kernel_launch(void* const* d_in, const int* in_sizes, int n_in,
                              void* d_out, int out_size, void* d_ws, size_t ws_size,
                              hipStream_t stream) {
  const float* x   = (const float*)d_in[0];
  const int*   ei  = (const int*)d_in[1];
  const float* W0  = (const float*)d_in[2];
  const float* as0 = (const float*)d_in[3];
  const float* ad0 = (const float*)d_in[4];
  const float* b0  = (const float*)d_in[5];
  const float* g0  = (const float*)d_in[6];
  const float* be0 = (const float*)d_in[7];
  const float* W1  = (const float*)d_in[8];
  const float* as1 = (const float*)d_in[9];
  const float* ad1 = (const float*)d_in[10];
  const float* b1  = (const float*)d_in[11];
  const float* g1  = (const float*)d_in[12];
  const float* be1 = (const float*)d_in[13];
  float* out = (float*)d_out;

  int N = in_sizes[0] / 128;
  int E = in_sizes[1] / 2;
  int Et = E + N;

  char* w = (char*)d_ws;
  auto alloc = [&](size_t bytes) {
    char* p = w; w += (bytes + 255) & ~255ull; return p;
  };
  // count + bn stats contiguous -> single memset clears all of them
  int*    count = (int*)alloc((size_t)N * 4 + 4 * 64 * 4);
  float*  bnsum0 = (float*)(count + N);
  float*  bnsq0  = bnsum0 + 64;
  float*  bnsum1 = bnsq0 + 64;
  float*  bnsq1  = bnsum1 + 64;
  __half* hpA   = (__half*)alloc((size_t)N * 32 * 2);   // fp16 ch 0-31 (3.2 MB)
  __half* hpB   = (__half*)alloc((size_t)N * 32 * 2);   // fp16 ch 32-63
  float*  hpre0 = (float*)alloc((size_t)N * 64 * 4);    // layer-0 pre-BN output
  float*  als   = (float*)alloc((size_t)N * 4 * 4);
  float*  ald   = (float*)alloc((size_t)N * 4 * 4);
  int*    rowp  = (int*)alloc((size_t)(N + 1) * 4);
  int*    cursor= (int*)alloc((size_t)N * 4);
  int*    parts = (int*)alloc(64 * 4);
  int*    csrc  = (int*)alloc((size_t)Et * 4);
  float2* ewA   = (float2*)alloc((size_t)Et * 8);
  float2* ewB   = (float2*)alloc((size_t)Et * 8);
  float2* denA  = (float2*)alloc((size_t)N * 8);
  float2* denB  = (float2*)alloc((size_t)N * 8);

  dim3 blk(256);
  int gEt   = (Et + 255) / 256;
  int gN64  = (N * 64 + 255) / 256;
  int nb    = (N + 1023) / 1024;
  int gTile = (N + 63) / 64;

  hipMemsetAsync(count, 0, (size_t)N * 4 + 4 * 64 * 4, stream);

  // ---- CSR build (shared by both layers) ----
  hist_k<<<gEt, blk, 0, stream>>>(ei, E, N, count);
  scan_block_k<<<nb, 1024, 0, stream>>>(count, rowp, parts, N);
  scan_partial_k<<<1, 64, 0, stream>>>(parts, rowp, nb, N);
  scan_add_k<<<nb, 1024, 0, stream>>>(rowp, cursor, parts, N);
  scatter_k<<<gEt, blk, 0, stream>>>(ei, E, N, cursor, csrc);

  // ---- layer 0 ----
  gemm_tiled<128, false><<<gTile, blk, 0, stream>>>(x, W0, as0, ad0,
                                                    nullptr, nullptr, nullptr, nullptr,
                                                    hpA, hpB, als, ald, N);
  ew_den_k<<<2048, blk, 0, stream>>>(rowp, csrc, als, ald, ewA, ewB, denA, denB, N);
  node_agg<0><<<4096, blk, 0, stream>>>(rowp, csrc, ewA, denA, hpA, b0,
                                        hpre0, bnsum0, bnsq0, N);
  node_agg<1><<<4096, blk, 0, stream>>>(rowp, csrc, ewB, denB, hpB, b0,
                                        hpre0, bnsum0, bnsq0, N);

  // ---- layer 1 (BN0 coeffs computed inline + ReLU fused into X staging) ----
  gemm_tiled<64, true><<<gTile, blk, 0, stream>>>(hpre0, W1, as1, ad1,
                                                  bnsum0, bnsq0, g0, be0,
                                                  hpA, hpB, als, ald, N);
  ew_den_k<<<2048, blk, 0, stream>>>(rowp, csrc, als, ald, ewA, ewB, denA, denB, N);
  node_agg<0><<<4096, blk, 0, stream>>>(rowp, csrc, ewA, denA, hpA, b1,
                                        out, bnsum1, bnsq1, N);
  node_agg<1><<<4096, blk, 0, stream>>>(rowp, csrc, ewB, denB, hpB, b1,
                                        out, bnsum1, bnsq1, N);
  bn_apply<<<gN64, blk, 0, stream>>>(out, bnsum1, bnsq1, g1, be1, N);
}

// Round 10
// 349.104 us; speedup vs baseline: 1.8490x; 1.8490x over previous
//
#include <hip/hip_runtime.h>
#include <hip/hip_fp16.h>

#define CAP 128   // max in-degree handled by the fast LDS path

__device__ __forceinline__ float sel4(float4 v, int h) {
  return h == 0 ? v.x : h == 1 ? v.y : h == 2 ? v.z : v.w;
}

// ---------------- tiled GEMM + attention logits ----------------
// Per block: stage X tile [64 x K] + W [K x 64] in LDS (coalesced float4).
// Each wave computes 16 rows x 64 cols. hp written fp16 (gather table).
// Optionally applies per-column BN (coeffs inline from bnsum/bnsq) + ReLU
// while staging X (fuses layer-0 BN into layer-1 GEMM).
template<int K, bool APPLY_BN>
__global__ void __launch_bounds__(256, 4)
gemm_tiled(const float* __restrict__ X, const float* __restrict__ W,
           const float* __restrict__ a_s, const float* __restrict__ a_d,
           const float* __restrict__ bnsum, const float* __restrict__ bnsq,
           const float* __restrict__ g, const float* __restrict__ be,
           __half* __restrict__ hp, float* __restrict__ al_s,
           float* __restrict__ al_d, int n)
{
  __shared__ float Wl[(K / 4) * 64 * 4];  // [(k4*64+lane)*4+c] = W[(k4*4+c)*64+lane]
  __shared__ float Xt[64 * K];            // row-major [64][K]

  for (int gi = threadIdx.x; gi < (K / 4) * 64; gi += 256) {
    int k4 = gi >> 6, ln = gi & 63;
    float4 w;
    w.x = W[(k4 * 4 + 0) * 64 + ln];
    w.y = W[(k4 * 4 + 1) * 64 + ln];
    w.z = W[(k4 * 4 + 2) * 64 + ln];
    w.w = W[(k4 * 4 + 3) * 64 + ln];
    *(float4*)&Wl[gi * 4] = w;
  }

  int row0 = blockIdx.x * 64;
  int nrows = min(64, n - row0);
  float4 sc, sh;
  if (APPLY_BN) {   // K==64 path: float4 col group fixed per thread
    int cg = (threadIdx.x & 15) * 4;
    float inv_n = 1.f / (float)n;
#pragma unroll
    for (int q = 0; q < 4; ++q) {
      float mu  = bnsum[cg + q] * inv_n;
      float var = bnsq[cg + q] * inv_n - mu * mu;
      float s   = g[cg + q] * rsqrtf(var + 1e-5f);
      ((float*)&sc)[q] = s;
      ((float*)&sh)[q] = be[cg + q] - mu * s;
    }
  }
  const float4* src = (const float4*)(X + (size_t)row0 * K);
  int nf4 = nrows * (K / 4);
  for (int i = threadIdx.x; i < nf4; i += 256) {
    float4 v = src[i];
    if (APPLY_BN) {
      v.x = fmaxf(v.x * sc.x + sh.x, 0.f);
      v.y = fmaxf(v.y * sc.y + sh.y, 0.f);
      v.z = fmaxf(v.z * sc.z + sh.z, 0.f);
      v.w = fmaxf(v.w * sc.w + sh.w, 0.f);
    }
    *(float4*)&Xt[i * 4] = v;
  }
  __syncthreads();

  int lane = threadIdx.x & 63;
  int wid  = threadIdx.x >> 6;
  int rbase = wid * 16;
  float acc[16];
#pragma unroll
  for (int r = 0; r < 16; ++r) acc[r] = 0.f;

  for (int k4 = 0; k4 < K / 4; ++k4) {
    float4 wv = *(const float4*)&Wl[(k4 * 64 + lane) * 4];
#pragma unroll
    for (int r = 0; r < 16; ++r) {
      float4 xv = *(const float4*)&Xt[(rbase + r) * K + k4 * 4];
      acc[r] += xv.x * wv.x + xv.y * wv.y + xv.z * wv.z + xv.w * wv.w;
    }
  }

  float as_l = a_s[lane], ad_l = a_d[lane];
  int h = lane >> 4, c = lane & 15;
#pragma unroll
  for (int r = 0; r < 16; ++r) {
    int lr = rbase + r;
    if (lr >= nrows) break;
    int row = row0 + lr;
    float a = acc[r];
    hp[(size_t)row * 64 + lane] = __float2half(a);
    float vs = a * as_l;
    float vd = a * ad_l;
#pragma unroll
    for (int off = 8; off >= 1; off >>= 1) {
      vs += __shfl_xor(vs, off, 64);
      vd += __shfl_xor(vd, off, 64);
    }
    if (c == 0) { al_s[row * 4 + h] = vs; al_d[row * 4 + h] = vd; }
  }
}

// ---------------- CSR build (once per call; reused by both layers) ----------------
__global__ void hist_k(const int* __restrict__ ei, int E, int N, int* __restrict__ count)
{
  int e = blockIdx.x * 256 + threadIdx.x;
  int Et = E + N;
  if (e >= Et) return;
  int d = (e < E) ? ei[E + e] : (e - E);
  atomicAdd(&count[d], 1);
}

__global__ void scan_block_k(const int* __restrict__ count, int* __restrict__ row_ptr,
                             int* __restrict__ partial, int n)
{
  __shared__ int woff[16];
  int tid = threadIdx.x;
  int i = blockIdx.x * 1024 + tid;
  int v = (i < n) ? count[i] : 0;
  int lane = tid & 63, wid = tid >> 6;
  int incl = v;
#pragma unroll
  for (int off = 1; off < 64; off <<= 1) {
    int t = __shfl_up(incl, off, 64);
    if (lane >= off) incl += t;
  }
  if (lane == 63) woff[wid] = incl;
  __syncthreads();
  if (tid < 16) {
    int wv = woff[tid];
    int winc = wv;
#pragma unroll
    for (int off = 1; off < 16; off <<= 1) {
      int t = __shfl_up(winc, off, 64);
      if (tid >= off) winc += t;
    }
    woff[tid] = winc - wv;
    if (tid == 15) partial[blockIdx.x] = winc;
  }
  __syncthreads();
  if (i < n) row_ptr[i] = woff[wid] + incl - v;
}

__global__ void scan_partial_k(int* __restrict__ partial, int* __restrict__ row_ptr,
                               int nb, int n)
{
  int tid = threadIdx.x;  // 64 threads
  int v = (tid < nb) ? partial[tid] : 0;
  int incl = v;
#pragma unroll
  for (int off = 1; off < 64; off <<= 1) {
    int t = __shfl_up(incl, off, 64);
    if (tid >= off) incl += t;
  }
  if (tid < nb) partial[tid] = incl - v;
  if (tid == 63) row_ptr[n] = incl;
}

__global__ void scan_add_k(int* __restrict__ row_ptr, int* __restrict__ cursor,
                           const int* __restrict__ partial, int n)
{
  int i = blockIdx.x * 1024 + threadIdx.x;
  if (i < n) {
    int r = row_ptr[i] + partial[blockIdx.x];
    row_ptr[i] = r;
    cursor[i] = r;
  }
}

__global__ void scatter_k(const int* __restrict__ ei, int E, int N,
                          int* __restrict__ cursor, int* __restrict__ col_src)
{
  int e = blockIdx.x * 256 + threadIdx.x;
  int Et = E + N;
  if (e >= Et) return;
  int s, d;
  if (e < E) { s = ei[e]; d = ei[E + e]; } else { s = d = e - E; }
  int pos = atomicAdd(&cursor[d], 1);
  col_src[pos] = s;
}

// ---------------- per-node softmax weights + denominators ----------------
// One wave per node: lanes gather al_s[src] (800 KB table, L2-resident),
// compute exp(leaky(.)) for 4 heads, write CSR-ordered float4 weights
// (coalesced) and wave-reduce the per-head sums into den4[d]. No atomics.
// Removes exp/gather/reduce from node_agg's per-node critical path.
__global__ void __launch_bounds__(256)
ew_den_k(const int* __restrict__ row_ptr, const int* __restrict__ col_src,
         const float* __restrict__ al_s, const float* __restrict__ al_d,
         float4* __restrict__ ew4, float4* __restrict__ den4, int n)
{
  int lane = threadIdx.x & 63;
  int wid  = threadIdx.x >> 6;
  int nwaves = gridDim.x * 4;
  for (int d = blockIdx.x * 4 + wid; d < n; d += nwaves) {
    int beg = row_ptr[d], end = row_ptr[d + 1];
    int deg = end - beg;
    float4 ald4 = *(const float4*)(al_d + (size_t)d * 4);
    float s0 = 0.f, s1 = 0.f, s2 = 0.f, s3 = 0.f;
    for (int jb = 0; jb < deg; jb += 64) {
      int jj = jb + lane;
      if (jj < deg) {
        int s = col_src[beg + jj];
        float4 a = *(const float4*)(al_s + (size_t)s * 4);
        float ex = a.x + ald4.x; ex = ex >= 0.f ? ex : 0.2f * ex;
        float ey = a.y + ald4.y; ey = ey >= 0.f ? ey : 0.2f * ey;
        float ez = a.z + ald4.z; ez = ez >= 0.f ? ez : 0.2f * ez;
        float ew = a.w + ald4.w; ew = ew >= 0.f ? ew : 0.2f * ew;
        ex = __expf(ex); ey = __expf(ey); ez = __expf(ez); ew = __expf(ew);
        ew4[beg + jj] = make_float4(ex, ey, ez, ew);
        s0 += ex; s1 += ey; s2 += ez; s3 += ew;
      }
    }
#pragma unroll
    for (int off = 32; off >= 1; off >>= 1) {
      s0 += __shfl_xor(s0, off, 64);
      s1 += __shfl_xor(s1, off, 64);
      s2 += __shfl_xor(s2, off, 64);
      s3 += __shfl_xor(s3, off, 64);
    }
    if (lane == 0) den4[d] = make_float4(s0, s1, s2, s3);
  }
}

// ---------------- per-node aggregation (2 edges/instr, 16 edges in flight) -------
// One wave per dst node. lane = parity*32 + chpair: each lane loads one dword
// (2 fp16 channels) so a wave instruction covers TWO full 128-B hp rows.
// 8-deep unroll -> 8 instructions / 16 cache lines outstanding per wave
// (2x the previous per-wave MLP; r8 showed concurrency, not bytes, is the
// limiter). Stage = pure LDS copy of col_src + precomputed float4 weights,
// zero-padded to x16. Fold parities with one shfl_xor(32); remap channels
// via a 64-float LDS bounce. den4/bias applied at the end.
__global__ void __launch_bounds__(256)
node_agg(const int* __restrict__ row_ptr, const int* __restrict__ col_src,
         const float4* __restrict__ ew4, const float4* __restrict__ den4,
         const __half* __restrict__ hp, const float* __restrict__ bias,
         float* __restrict__ hpre, float* __restrict__ bnsum, float* __restrict__ bnsq,
         int n)
{
  __shared__ int   sh_s[4][CAP];
  __shared__ float sh_w[4][CAP * 4];
  __shared__ float sh_o[4][64];
  __shared__ float shs[64], shq[64];

  int lane = threadIdx.x & 63;
  int wid  = threadIdx.x >> 6;
  int c    = lane & 31;          // channel-pair index: channels 2c, 2c+1
  int e2   = lane >> 5;          // edge parity handled by this half-wave
  int h    = c >> 3;             // head of both channels (pairs never straddle heads)
  float b  = bias[lane];
  float lsum = 0.f, lsq = 0.f;
  int nwaves = gridDim.x * 4;

  for (int d = blockIdx.x * 4 + wid; d < n; d += nwaves) {
    int beg = row_ptr[d], end = row_ptr[d + 1];
    int deg = end - beg;
    float4 dn = den4[d];
    float acc0 = 0.f, acc1 = 0.f;

    if (deg <= CAP) {
      int degR = (deg + 15) & ~15;
      for (int jb = 0; jb < degR; jb += 64) {
        int jj = jb + lane;
        if (jj < deg) {
          sh_s[wid][jj] = col_src[beg + jj];
          *(float4*)&sh_w[wid][jj * 4] = ew4[beg + jj];
        } else if (jj < degR) {
          sh_s[wid][jj] = 0;
          *(float4*)&sh_w[wid][jj * 4] = make_float4(0.f, 0.f, 0.f, 0.f);
        }
      }
      __builtin_amdgcn_wave_barrier();
      for (int j = 0; j < degR; j += 16) {
#pragma unroll
        for (int k = 0; k < 8; ++k) {
          int e = j + k * 2 + e2;
          int s = sh_s[wid][e];
          float wh = sh_w[wid][e * 4 + h];
          unsigned raw = *(const unsigned*)(hp + (size_t)s * 64 + c * 2);
          float2 f = __half22float2(*(const __half2*)&raw);
          acc0 += wh * f.x;
          acc1 += wh * f.y;
        }
      }
      acc0 += __shfl_xor(acc0, 32, 64);
      acc1 += __shfl_xor(acc1, 32, 64);
    } else {
      // fallback: all lanes iterate all edges (no parity fold needed)
      for (int j = beg; j < end; ++j) {
        int s = col_src[j];
        float wh = sel4(ew4[j], h);
        unsigned raw = *(const unsigned*)(hp + (size_t)s * 64 + c * 2);
        float2 f = __half22float2(*(const __half2*)&raw);
        acc0 += wh * f.x;
        acc1 += wh * f.y;
      }
    }

    if (lane < 32) *(float2*)&sh_o[wid][c * 2] = make_float2(acc0, acc1);
    __builtin_amdgcn_wave_barrier();
    float den = sel4(dn, lane >> 4);
    float outv = sh_o[wid][lane] / (den + 1e-16f) + b;

    hpre[(size_t)d * 64 + lane] = outv;
    lsum += outv; lsq += outv * outv;
  }

  if (threadIdx.x < 64) { shs[threadIdx.x] = 0.f; shq[threadIdx.x] = 0.f; }
  __syncthreads();
  atomicAdd(&shs[lane], lsum);
  atomicAdd(&shq[lane], lsq);
  __syncthreads();
  if (threadIdx.x < 64) {
    atomicAdd(&bnsum[threadIdx.x], shs[threadIdx.x]);
    atomicAdd(&bnsq[threadIdx.x],  shq[threadIdx.x]);
  }
}

// ---------------- BatchNorm apply (final layer, in-place on out) ----------------
__global__ void bn_apply(float* __restrict__ buf, const float* __restrict__ bnsum,
                         const float* __restrict__ bnsq, const float* __restrict__ g,
                         const float* __restrict__ be, int n)
{
  size_t i = (size_t)blockIdx.x * 256 + threadIdx.x;
  size_t total = (size_t)n * 64;
  if (i >= total) return;
  int c = (int)(i & 63);
  float inv_n = 1.f / (float)n;
  float mu  = bnsum[c] * inv_n;
  float var = bnsq[c] * inv_n - mu * mu;    // biased var, matches jnp .var()
  buf[i] = (buf[i] - mu) * rsqrtf(var + 1e-5f) * g[c] + be[c];
}

extern "C" void kernel_launch(void* const* d_in, const int* in_sizes, int n_in,
                              void* d_out, int out_size, void* d_ws, size_t ws_size,
                              hipStream_t stream) {
  const float* x   = (const float*)d_in[0];
  const int*   ei  = (const int*)d_in[1];
  const float* W0  = (const float*)d_in[2];
  const float* as0 = (const float*)d_in[3];
  const float* ad0 = (const float*)d_in[4];
  const float* b0  = (const float*)d_in[5];
  const float* g0  = (const float*)d_in[6];
  const float* be0 = (const float*)d_in[7];
  const float* W1  = (const float*)d_in[8];
  const float* as1 = (const float*)d_in[9];
  const float* ad1 = (const float*)d_in[10];
  const float* b1  = (const float*)d_in[11];
  const float* g1  = (const float*)d_in[12];
  const float* be1 = (const float*)d_in[13];
  float* out = (float*)d_out;

  int N = in_sizes[0] / 128;
  int E = in_sizes[1] / 2;
  int Et = E + N;

  char* w = (char*)d_ws;
  auto alloc = [&](size_t bytes) {
    char* p = w; w += (bytes + 255) & ~255ull; return p;
  };
  // count + bn stats contiguous -> single memset clears all of them
  int*    count = (int*)alloc((size_t)N * 4 + 4 * 64 * 4);
  float*  bnsum0 = (float*)(count + N);
  float*  bnsq0  = bnsum0 + 64;
  float*  bnsum1 = bnsq0 + 64;
  float*  bnsq1  = bnsum1 + 64;
  __half* hp    = (__half*)alloc((size_t)N * 64 * 2);   // fp16 hp gather table
  float*  hpre0 = (float*)alloc((size_t)N * 64 * 4);    // layer-0 pre-BN output
  float*  als   = (float*)alloc((size_t)N * 4 * 4);
  float*  ald   = (float*)alloc((size_t)N * 4 * 4);
  int*    rowp  = (int*)alloc((size_t)(N + 1) * 4);
  int*    cursor= (int*)alloc((size_t)N * 4);
  int*    parts = (int*)alloc(64 * 4);
  int*    csrc  = (int*)alloc((size_t)Et * 4);
  float4* ew4   = (float4*)alloc((size_t)Et * 16);
  float4* den4  = (float4*)alloc((size_t)N * 16);

  dim3 blk(256);
  int gEt   = (Et + 255) / 256;
  int gN64  = (N * 64 + 255) / 256;
  int nb    = (N + 1023) / 1024;
  int gTile = (N + 63) / 64;

  hipMemsetAsync(count, 0, (size_t)N * 4 + 4 * 64 * 4, stream);

  // ---- CSR build (shared by both layers) ----
  hist_k<<<gEt, blk, 0, stream>>>(ei, E, N, count);
  scan_block_k<<<nb, 1024, 0, stream>>>(count, rowp, parts, N);
  scan_partial_k<<<1, 64, 0, stream>>>(parts, rowp, nb, N);
  scan_add_k<<<nb, 1024, 0, stream>>>(rowp, cursor, parts, N);
  scatter_k<<<gEt, blk, 0, stream>>>(ei, E, N, cursor, csrc);

  // ---- layer 0 ----
  gemm_tiled<128, false><<<gTile, blk, 0, stream>>>(x, W0, as0, ad0,
                                                    nullptr, nullptr, nullptr, nullptr,
                                                    hp, als, ald, N);
  ew_den_k<<<2048, blk, 0, stream>>>(rowp, csrc, als, ald, ew4, den4, N);
  node_agg<<<2048, blk, 0, stream>>>(rowp, csrc, ew4, den4, hp, b0,
                                     hpre0, bnsum0, bnsq0, N);

  // ---- layer 1 (BN0 coeffs computed inline + ReLU fused into X staging) ----
  gemm_tiled<64, true><<<gTile, blk, 0, stream>>>(hpre0, W1, as1, ad1,
                                                  bnsum0, bnsq0, g0, be0,
                                                  hp, als, ald, N);
  ew_den_k<<<2048, blk, 0, stream>>>(rowp, csrc, als, ald, ew4, den4, N);
  node_agg<<<2048, blk, 0, stream>>>(rowp, csrc, ew4, den4, hp, b1,
                                     out, bnsum1, bnsq1, N);
  bn_apply<<<gN64, blk, 0, stream>>>(out, bnsum1, bnsq1, g1, be1, N);
}

// Round 11
// 324.327 us; speedup vs baseline: 1.9902x; 1.0764x over previous
//
#include <hip/hip_runtime.h>
#include <hip/hip_fp16.h>

#define CAP 128   // max in-degree handled by the fast LDS path

__device__ __forceinline__ float sel4(float4 v, int h) {
  return h == 0 ? v.x : h == 1 ? v.y : h == 2 ? v.z : v.w;
}

// ---------------- tiled GEMM + attention logits ----------------
// Per block: stage X tile [64 x K] + W [K x 64] in LDS (coalesced float4).
// Each wave computes 16 rows x 64 cols. hp written fp16 (gather table).
// Optionally applies per-column BN (coeffs inline from bnsum/bnsq) + ReLU
// while staging X (fuses layer-0 BN into layer-1 GEMM).
template<int K, bool APPLY_BN>
__global__ void __launch_bounds__(256, 4)
gemm_tiled(const float* __restrict__ X, const float* __restrict__ W,
           const float* __restrict__ a_s, const float* __restrict__ a_d,
           const float* __restrict__ bnsum, const float* __restrict__ bnsq,
           const float* __restrict__ g, const float* __restrict__ be,
           __half* __restrict__ hp, float* __restrict__ al_s,
           float* __restrict__ al_d, int n)
{
  __shared__ float Wl[(K / 4) * 64 * 4];  // [(k4*64+lane)*4+c] = W[(k4*4+c)*64+lane]
  __shared__ float Xt[64 * K];            // row-major [64][K]

  for (int gi = threadIdx.x; gi < (K / 4) * 64; gi += 256) {
    int k4 = gi >> 6, ln = gi & 63;
    float4 w;
    w.x = W[(k4 * 4 + 0) * 64 + ln];
    w.y = W[(k4 * 4 + 1) * 64 + ln];
    w.z = W[(k4 * 4 + 2) * 64 + ln];
    w.w = W[(k4 * 4 + 3) * 64 + ln];
    *(float4*)&Wl[gi * 4] = w;
  }

  int row0 = blockIdx.x * 64;
  int nrows = min(64, n - row0);
  float4 sc, sh;
  if (APPLY_BN) {   // K==64 path: float4 col group fixed per thread
    int cg = (threadIdx.x & 15) * 4;
    float inv_n = 1.f / (float)n;
#pragma unroll
    for (int q = 0; q < 4; ++q) {
      float mu  = bnsum[cg + q] * inv_n;
      float var = bnsq[cg + q] * inv_n - mu * mu;
      float s   = g[cg + q] * rsqrtf(var + 1e-5f);
      ((float*)&sc)[q] = s;
      ((float*)&sh)[q] = be[cg + q] - mu * s;
    }
  }
  const float4* src = (const float4*)(X + (size_t)row0 * K);
  int nf4 = nrows * (K / 4);
  for (int i = threadIdx.x; i < nf4; i += 256) {
    float4 v = src[i];
    if (APPLY_BN) {
      v.x = fmaxf(v.x * sc.x + sh.x, 0.f);
      v.y = fmaxf(v.y * sc.y + sh.y, 0.f);
      v.z = fmaxf(v.z * sc.z + sh.z, 0.f);
      v.w = fmaxf(v.w * sc.w + sh.w, 0.f);
    }
    *(float4*)&Xt[i * 4] = v;
  }
  __syncthreads();

  int lane = threadIdx.x & 63;
  int wid  = threadIdx.x >> 6;
  int rbase = wid * 16;
  float acc[16];
#pragma unroll
  for (int r = 0; r < 16; ++r) acc[r] = 0.f;

  for (int k4 = 0; k4 < K / 4; ++k4) {
    float4 wv = *(const float4*)&Wl[(k4 * 64 + lane) * 4];
#pragma unroll
    for (int r = 0; r < 16; ++r) {
      float4 xv = *(const float4*)&Xt[(rbase + r) * K + k4 * 4];
      acc[r] += xv.x * wv.x + xv.y * wv.y + xv.z * wv.z + xv.w * wv.w;
    }
  }

  float as_l = a_s[lane], ad_l = a_d[lane];
  int h = lane >> 4, c = lane & 15;
#pragma unroll
  for (int r = 0; r < 16; ++r) {
    int lr = rbase + r;
    if (lr >= nrows) break;
    int row = row0 + lr;
    float a = acc[r];
    hp[(size_t)row * 64 + lane] = __float2half(a);
    float vs = a * as_l;
    float vd = a * ad_l;
#pragma unroll
    for (int off = 8; off >= 1; off >>= 1) {
      vs += __shfl_xor(vs, off, 64);
      vd += __shfl_xor(vd, off, 64);
    }
    if (c == 0) { al_s[row * 4 + h] = vs; al_d[row * 4 + h] = vd; }
  }
}

// ---------------- CSR build (once per call; reused by both layers) ----------------
__global__ void hist_k(const int* __restrict__ ei, int E, int N, int* __restrict__ count)
{
  int e = blockIdx.x * 256 + threadIdx.x;
  int Et = E + N;
  if (e >= Et) return;
  int d = (e < E) ? ei[E + e] : (e - E);
  atomicAdd(&count[d], 1);
}

__global__ void scan_block_k(const int* __restrict__ count, int* __restrict__ row_ptr,
                             int* __restrict__ partial, int n)
{
  __shared__ int woff[16];
  int tid = threadIdx.x;
  int i = blockIdx.x * 1024 + tid;
  int v = (i < n) ? count[i] : 0;
  int lane = tid & 63, wid = tid >> 6;
  int incl = v;
#pragma unroll
  for (int off = 1; off < 64; off <<= 1) {
    int t = __shfl_up(incl, off, 64);
    if (lane >= off) incl += t;
  }
  if (lane == 63) woff[wid] = incl;
  __syncthreads();
  if (tid < 16) {
    int wv = woff[tid];
    int winc = wv;
#pragma unroll
    for (int off = 1; off < 16; off <<= 1) {
      int t = __shfl_up(winc, off, 64);
      if (tid >= off) winc += t;
    }
    woff[tid] = winc - wv;
    if (tid == 15) partial[blockIdx.x] = winc;
  }
  __syncthreads();
  if (i < n) row_ptr[i] = woff[wid] + incl - v;
}

__global__ void scan_partial_k(int* __restrict__ partial, int* __restrict__ row_ptr,
                               int nb, int n)
{
  int tid = threadIdx.x;  // 64 threads
  int v = (tid < nb) ? partial[tid] : 0;
  int incl = v;
#pragma unroll
  for (int off = 1; off < 64; off <<= 1) {
    int t = __shfl_up(incl, off, 64);
    if (tid >= off) incl += t;
  }
  if (tid < nb) partial[tid] = incl - v;
  if (tid == 63) row_ptr[n] = incl;
}

__global__ void scan_add_k(int* __restrict__ row_ptr, int* __restrict__ cursor,
                           const int* __restrict__ partial, int n)
{
  int i = blockIdx.x * 1024 + threadIdx.x;
  if (i < n) {
    int r = row_ptr[i] + partial[blockIdx.x];
    row_ptr[i] = r;
    cursor[i] = r;
  }
}

__global__ void scatter_k(const int* __restrict__ ei, int E, int N,
                          int* __restrict__ cursor, int* __restrict__ col_src)
{
  int e = blockIdx.x * 256 + threadIdx.x;
  int Et = E + N;
  if (e >= Et) return;
  int s, d;
  if (e < E) { s = ei[e]; d = ei[E + e]; } else { s = d = e - E; }
  int pos = atomicAdd(&cursor[d], 1);
  col_src[pos] = s;
}

// ---------------- per-node aggregation (fused softmax, L2-friendly) ----------
// One wave per dst node. Stage: lane jj loads col_src (non-temporal) and
// gathers al_s[src] (800 KB table, L2-resident), computes exp(leaky()) for 4
// heads into LDS; per-head denominators via one shuffle reduce. Gather: lane
// = parity*32 + chpair; each lane loads one dword (2 fp16 ch) so a wave
// instruction covers TWO 128-B hp rows; 8-deep unroll = 16 lines in flight.
// Streaming traffic (col_src in, hpre out) is non-temporal so the 6.4 MB hp
// table keeps L2 residency — the measured wall is L2-miss traffic (FETCH =
// 6.8x table size in r10).
__global__ void __launch_bounds__(256)
node_agg(const int* __restrict__ row_ptr, const int* __restrict__ col_src,
         const float* __restrict__ al_s, const float* __restrict__ al_d,
         const __half* __restrict__ hp, const float* __restrict__ bias,
         float* __restrict__ hpre, float* __restrict__ bnsum, float* __restrict__ bnsq,
         int n)
{
  __shared__ int   sh_s[4][CAP];
  __shared__ float sh_w[4][CAP * 4];
  __shared__ float sh_o[4][64];
  __shared__ float shs[64], shq[64];

  int lane = threadIdx.x & 63;
  int wid  = threadIdx.x >> 6;
  int c    = lane & 31;          // channel-pair index: channels 2c, 2c+1
  int e2   = lane >> 5;          // edge parity handled by this half-wave
  int h4   = c >> 3;             // head of both channels (pairs never straddle heads)
  float b  = bias[lane];
  float lsum = 0.f, lsq = 0.f;
  int nwaves = gridDim.x * 4;

  for (int d = blockIdx.x * 4 + wid; d < n; d += nwaves) {
    int beg = row_ptr[d], end = row_ptr[d + 1];
    int deg = end - beg;
    float4 ald4 = *(const float4*)(al_d + (size_t)d * 4);
    float p0 = 0.f, p1 = 0.f, p2 = 0.f, p3 = 0.f;
    float acc0 = 0.f, acc1 = 0.f;

    if (deg <= CAP) {
      int degR = (deg + 15) & ~15;
      for (int jb = 0; jb < degR; jb += 64) {
        int jj = jb + lane;
        if (jj < deg) {
          int s = __builtin_nontemporal_load(&col_src[beg + jj]);
          float4 a = *(const float4*)(al_s + (size_t)s * 4);
          float ex = a.x + ald4.x; ex = ex >= 0.f ? ex : 0.2f * ex;
          float ey = a.y + ald4.y; ey = ey >= 0.f ? ey : 0.2f * ey;
          float ez = a.z + ald4.z; ez = ez >= 0.f ? ez : 0.2f * ez;
          float ew = a.w + ald4.w; ew = ew >= 0.f ? ew : 0.2f * ew;
          ex = __expf(ex); ey = __expf(ey); ez = __expf(ez); ew = __expf(ew);
          sh_s[wid][jj] = s;
          *(float4*)&sh_w[wid][jj * 4] = make_float4(ex, ey, ez, ew);
          p0 += ex; p1 += ey; p2 += ez; p3 += ew;
        } else if (jj < degR) {
          sh_s[wid][jj] = 0;
          *(float4*)&sh_w[wid][jj * 4] = make_float4(0.f, 0.f, 0.f, 0.f);
        }
      }
#pragma unroll
      for (int off = 32; off >= 1; off >>= 1) {
        p0 += __shfl_xor(p0, off, 64);
        p1 += __shfl_xor(p1, off, 64);
        p2 += __shfl_xor(p2, off, 64);
        p3 += __shfl_xor(p3, off, 64);
      }
      __builtin_amdgcn_wave_barrier();
      for (int j = 0; j < degR; j += 16) {
#pragma unroll
        for (int k = 0; k < 8; ++k) {
          int e = j + k * 2 + e2;
          int s = sh_s[wid][e];
          float wh = sh_w[wid][e * 4 + h4];
          unsigned raw = *(const unsigned*)(hp + (size_t)s * 64 + c * 2);
          float2 f = __half22float2(*(const __half2*)&raw);
          acc0 += wh * f.x;
          acc1 += wh * f.y;
        }
      }
      acc0 += __shfl_xor(acc0, 32, 64);
      acc1 += __shfl_xor(acc1, 32, 64);
    } else {
      // fallback: all lanes iterate all edges (no parity fold; deg > CAP never
      // happens for this graph but must stay correct)
      for (int j = beg; j < end; ++j) {
        int s = col_src[j];
        float4 a = *(const float4*)(al_s + (size_t)s * 4);
        float ex = a.x + ald4.x; ex = ex >= 0.f ? ex : 0.2f * ex;
        float ey = a.y + ald4.y; ey = ey >= 0.f ? ey : 0.2f * ey;
        float ez = a.z + ald4.z; ez = ez >= 0.f ? ez : 0.2f * ez;
        float ew = a.w + ald4.w; ew = ew >= 0.f ? ew : 0.2f * ew;
        ex = __expf(ex); ey = __expf(ey); ez = __expf(ez); ew = __expf(ew);
        p0 += ex; p1 += ey; p2 += ez; p3 += ew;
        float4 w4 = make_float4(ex, ey, ez, ew);
        float wh = sel4(w4, h4);
        unsigned raw = *(const unsigned*)(hp + (size_t)s * 64 + c * 2);
        float2 f = __half22float2(*(const __half2*)&raw);
        acc0 += wh * f.x;
        acc1 += wh * f.y;
      }
    }

    if (lane < 32) *(float2*)&sh_o[wid][c * 2] = make_float2(acc0, acc1);
    __builtin_amdgcn_wave_barrier();
    float den = (lane < 16) ? p0 : (lane < 32) ? p1 : (lane < 48) ? p2 : p3;
    float outv = sh_o[wid][lane] / (den + 1e-16f) + b;

    __builtin_nontemporal_store(outv, &hpre[(size_t)d * 64 + lane]);
    lsum += outv; lsq += outv * outv;
  }

  if (threadIdx.x < 64) { shs[threadIdx.x] = 0.f; shq[threadIdx.x] = 0.f; }
  __syncthreads();
  atomicAdd(&shs[lane], lsum);
  atomicAdd(&shq[lane], lsq);
  __syncthreads();
  if (threadIdx.x < 64) {
    atomicAdd(&bnsum[threadIdx.x], shs[threadIdx.x]);
    atomicAdd(&bnsq[threadIdx.x],  shq[threadIdx.x]);
  }
}

// ---------------- BatchNorm apply (final layer, in-place on out) ----------------
__global__ void bn_apply(float* __restrict__ buf, const float* __restrict__ bnsum,
                         const float* __restrict__ bnsq, const float* __restrict__ g,
                         const float* __restrict__ be, int n)
{
  size_t i = (size_t)blockIdx.x * 256 + threadIdx.x;
  size_t total = (size_t)n * 64;
  if (i >= total) return;
  int c = (int)(i & 63);
  float inv_n = 1.f / (float)n;
  float mu  = bnsum[c] * inv_n;
  float var = bnsq[c] * inv_n - mu * mu;    // biased var, matches jnp .var()
  buf[i] = (buf[i] - mu) * rsqrtf(var + 1e-5f) * g[c] + be[c];
}

extern "C" void kernel_launch(void* const* d_in, const int* in_sizes, int n_in,
                              void* d_out, int out_size, void* d_ws, size_t ws_size,
                              hipStream_t stream) {
  const float* x   = (const float*)d_in[0];
  const int*   ei  = (const int*)d_in[1];
  const float* W0  = (const float*)d_in[2];
  const float* as0 = (const float*)d_in[3];
  const float* ad0 = (const float*)d_in[4];
  const float* b0  = (const float*)d_in[5];
  const float* g0  = (const float*)d_in[6];
  const float* be0 = (const float*)d_in[7];
  const float* W1  = (const float*)d_in[8];
  const float* as1 = (const float*)d_in[9];
  const float* ad1 = (const float*)d_in[10];
  const float* b1  = (const float*)d_in[11];
  const float* g1  = (const float*)d_in[12];
  const float* be1 = (const float*)d_in[13];
  float* out = (float*)d_out;

  int N = in_sizes[0] / 128;
  int E = in_sizes[1] / 2;
  int Et = E + N;

  char* w = (char*)d_ws;
  auto alloc = [&](size_t bytes) {
    char* p = w; w += (bytes + 255) & ~255ull; return p;
  };
  // count + bn stats contiguous -> single memset clears all of them
  int*    count = (int*)alloc((size_t)N * 4 + 4 * 64 * 4);
  float*  bnsum0 = (float*)(count + N);
  float*  bnsq0  = bnsum0 + 64;
  float*  bnsum1 = bnsq0 + 64;
  float*  bnsq1  = bnsum1 + 64;
  __half* hp    = (__half*)alloc((size_t)N * 64 * 2);   // fp16 hp gather table
  float*  hpre0 = (float*)alloc((size_t)N * 64 * 4);    // layer-0 pre-BN output
  float*  als   = (float*)alloc((size_t)N * 4 * 4);
  float*  ald   = (float*)alloc((size_t)N * 4 * 4);
  int*    rowp  = (int*)alloc((size_t)(N + 1) * 4);
  int*    cursor= (int*)alloc((size_t)N * 4);
  int*    parts = (int*)alloc(64 * 4);
  int*    csrc  = (int*)alloc((size_t)Et * 4);

  dim3 blk(256);
  int gEt   = (Et + 255) / 256;
  int gN64  = (N * 64 + 255) / 256;
  int nb    = (N + 1023) / 1024;
  int gTile = (N + 63) / 64;

  hipMemsetAsync(count, 0, (size_t)N * 4 + 4 * 64 * 4, stream);

  // ---- CSR build (shared by both layers) ----
  hist_k<<<gEt, blk, 0, stream>>>(ei, E, N, count);
  scan_block_k<<<nb, 1024, 0, stream>>>(count, rowp, parts, N);
  scan_partial_k<<<1, 64, 0, stream>>>(parts, rowp, nb, N);
  scan_add_k<<<nb, 1024, 0, stream>>>(rowp, cursor, parts, N);
  scatter_k<<<gEt, blk, 0, stream>>>(ei, E, N, cursor, csrc);

  // ---- layer 0 ----
  gemm_tiled<128, false><<<gTile, blk, 0, stream>>>(x, W0, as0, ad0,
                                                    nullptr, nullptr, nullptr, nullptr,
                                                    hp, als, ald, N);
  node_agg<<<2048, blk, 0, stream>>>(rowp, csrc, als, ald, hp, b0,
                                     hpre0, bnsum0, bnsq0, N);

  // ---- layer 1 (BN0 coeffs computed inline + ReLU fused into X staging) ----
  gemm_tiled<64, true><<<gTile, blk, 0, stream>>>(hpre0, W1, as1, ad1,
                                                  bnsum0, bnsq0, g0, be0,
                                                  hp, als, ald, N);
  node_agg<<<2048, blk, 0, stream>>>(rowp, csrc, als, ald, hp, b1,
                                     out, bnsum1, bnsq1, N);
  bn_apply<<<gN64, blk, 0, stream>>>(out, bnsum1, bnsq1, g1, be1, N);
}